// Round 2
// baseline (13250.298 us; speedup 1.0000x reference)
//
#include <hip/hip_runtime.h>
#include <hip/hip_bf16.h>

// C_VAE_NET: 2-layer LSTM encoder -> reparam -> 2-layer LSTM decoder -> dense.
// B=512, T=128, D=128, Z=64, U=512, gates 4U=2048.
// Round 1: persistent per-layer LSTM kernels.
//  - 8 independent batch groups (64 rows each, group = blockIdx&7 -> XCD-local),
//    32 N-tile blocks per group, each owning 64 gate columns.
//  - Weight slice (64 x K, K=512+DIN) staged in LDS ONCE per layer, XOR-swizzled.
//  - Cell state lives in registers across all 128 timesteps.
//  - Per-step sync = 32-block group barrier (device-scope atomics), no launches.

#define B_  512
#define T_  128
#define D_  128
#define Z_  64
#define U_  512
#define G4_ 2048

typedef __attribute__((ext_vector_type(8))) short short8; // 8 x bf16
typedef __attribute__((ext_vector_type(4))) float f32x4;

__device__ __forceinline__ float sigm(float x)  { return 1.0f / (1.0f + __expf(-x)); }
__device__ __forceinline__ float tanhf_(float x){ return 2.0f / (1.0f + __expf(-2.0f * x)) - 1.0f; }

// ---------------------------------------------------------------------------
// prep kernels
// ---------------------------------------------------------------------------

__global__ void convert_bf16(const float* __restrict__ src, __hip_bfloat16* __restrict__ dst, int n) {
    int i = blockIdx.x * 256 + threadIdx.x;
    if (i < n) dst[i] = __float2bfloat16(src[i]);
}

// dst[n][koff+k] = bf16(src[k][pcol(n)]) ; src is [K][Nsrc] row-major fp32.
// perm: pcol = (n&3)*512 + (n>>2)  (gate-interleave i,f,c,o per unit), else n.
__global__ void conv_weight(const float* __restrict__ src, __hip_bfloat16* __restrict__ dst,
                            int K, int Nrows, int Nsrc, int ldd, int koff, int perm) {
    int idx = blockIdx.x * 256 + threadIdx.x;
    if (idx >= K * Nrows) return;
    int n = idx / K, k = idx - n * K;
    int pc = perm ? ((n & 3) * 512 + (n >> 2)) : n;
    dst[(size_t)n * ldd + koff + k] = __float2bfloat16(src[(size_t)k * Nsrc + pc]);
}

__global__ void conv_bias(const float* __restrict__ src, float* __restrict__ dst) {
    int n = blockIdx.x * 256 + threadIdx.x;
    if (n < G4_) dst[n] = src[(n & 3) * 512 + (n >> 2)];
}

// ---------------------------------------------------------------------------
// persistent LSTM layer.
// hs : [B][T][U] bf16 output h-sequence (written at [row][t][:])
// xin: [B][T][DIN] bf16 layer input
// WT : [2048][512+DIN] bf16, row n = permuted gate col; cols = [Wh | Wx]
// bar: 8 group counters, stride 32 uints, pre-zeroed
// grid 256 blocks x 256 thr; block = (group g=bid&7 -> rows 64g.., ntile j=bid>>3 -> cols 64j..)
// ---------------------------------------------------------------------------
template <int DIN>
__global__ __launch_bounds__(256, 1) void lstm_layer_persist(
    __hip_bfloat16* __restrict__ hs,
    const __hip_bfloat16* __restrict__ xin,
    const __hip_bfloat16* __restrict__ WT,
    const float* __restrict__ bias,
    unsigned* __restrict__ bar) {
    constexpr int LDW = U_ + DIN;
    constexpr int S = LDW * 2;                 // LDS row byte stride (multiple of 128)
    __shared__ __hip_bfloat16 Wl[64 * LDW];    // <= 128 KiB

    const int bid = blockIdx.x;
    const int g = bid & 7;                      // batch group (XCD-aligned)
    const int j = bid >> 3;                     // gate-column tile
    const int m0 = g * 64, n0 = j * 64;
    const int tid = threadIdx.x;
    const int w = tid >> 6, l = tid & 63, lr = l & 15, lq = l >> 4;
    const int wm = (w >> 1) * 32, wn = (w & 1) * 32;
    const int gate = l & 3;

    // ---- stage weight slice into LDS, XOR-swizzled: byte ^= (row&7)<<4 ----
    constexpr int CH = LDW / 8;                 // 16B chunks per row
    for (int idx = tid; idx < 64 * CH; idx += 256) {
        int row = idx / CH, ch = idx - row * CH;
        short8 v = *(const short8*)(WT + (size_t)(n0 + row) * LDW + ch * 8);
        int byte = row * S + ((ch * 16) ^ ((row & 7) << 4));
        *(short8*)((char*)Wl + byte) = v;
    }

    const float b0v = bias[n0 + wn + lr];
    const float b1v = bias[n0 + wn + 16 + lr];

    float c_reg[2][2][4];
#pragma unroll
    for (int i = 0; i < 2; i++)
#pragma unroll
        for (int jj = 0; jj < 2; jj++)
#pragma unroll
            for (int r = 0; r < 4; r++) c_reg[i][jj][r] = 0.0f;

    const int rowA0 = m0 + wm + lr, rowA1 = rowA0 + 16;
    const int rB0 = wn + lr, rB1 = wn + 16 + lr;
    const char* WlB0 = (const char*)Wl + rB0 * S;
    const char* WlB1 = (const char*)Wl + rB1 * S;
    const int sw0 = (rB0 & 7) << 4;
    const int sw1 = (rB1 & 7) << 4;

    __syncthreads();

    for (int t = 0; t < T_; ++t) {
        f32x4 acc[2][2];
#pragma unroll
        for (int i = 0; i < 2; i++)
#pragma unroll
            for (int r = 0; r < 4; r++) { acc[i][0][r] = b0v; acc[i][1][r] = b1v; }

        if (t > 0) {
            const __hip_bfloat16* A0 = hs + ((size_t)rowA0 * T_ + (t - 1)) * U_ + lq * 8;
            const __hip_bfloat16* A1 = hs + ((size_t)rowA1 * T_ + (t - 1)) * U_ + lq * 8;
#pragma unroll 4
            for (int k0 = 0; k0 < U_; k0 += 32) {
                short8 a0 = *(const short8*)(A0 + k0);
                short8 a1 = *(const short8*)(A1 + k0);
                int off = (k0 + lq * 8) * 2;
                short8 bb0 = *(const short8*)(WlB0 + (off ^ sw0));
                short8 bb1 = *(const short8*)(WlB1 + (off ^ sw1));
                acc[0][0] = __builtin_amdgcn_mfma_f32_16x16x32_bf16(a0, bb0, acc[0][0], 0, 0, 0);
                acc[0][1] = __builtin_amdgcn_mfma_f32_16x16x32_bf16(a0, bb1, acc[0][1], 0, 0, 0);
                acc[1][0] = __builtin_amdgcn_mfma_f32_16x16x32_bf16(a1, bb0, acc[1][0], 0, 0, 0);
                acc[1][1] = __builtin_amdgcn_mfma_f32_16x16x32_bf16(a1, bb1, acc[1][1], 0, 0, 0);
            }
        }
        {
            const __hip_bfloat16* X0 = xin + ((size_t)rowA0 * T_ + t) * DIN + lq * 8;
            const __hip_bfloat16* X1 = xin + ((size_t)rowA1 * T_ + t) * DIN + lq * 8;
#pragma unroll 4
            for (int k0 = 0; k0 < DIN; k0 += 32) {
                short8 a0 = *(const short8*)(X0 + k0);
                short8 a1 = *(const short8*)(X1 + k0);
                int off = (U_ + k0 + lq * 8) * 2;
                short8 bb0 = *(const short8*)(WlB0 + (off ^ sw0));
                short8 bb1 = *(const short8*)(WlB1 + (off ^ sw1));
                acc[0][0] = __builtin_amdgcn_mfma_f32_16x16x32_bf16(a0, bb0, acc[0][0], 0, 0, 0);
                acc[0][1] = __builtin_amdgcn_mfma_f32_16x16x32_bf16(a0, bb1, acc[0][1], 0, 0, 0);
                acc[1][0] = __builtin_amdgcn_mfma_f32_16x16x32_bf16(a1, bb0, acc[1][0], 0, 0, 0);
                acc[1][1] = __builtin_amdgcn_mfma_f32_16x16x32_bf16(a1, bb1, acc[1][1], 0, 0, 0);
            }
        }

        // ---- gate nonlinearity: per-lane (full util), v is this lane's gate ----
#pragma unroll
        for (int i = 0; i < 2; i++)
#pragma unroll
            for (int jj = 0; jj < 2; jj++)
#pragma unroll
                for (int r = 0; r < 4; r++) {
                    float v = acc[i][jj][r];
                    float sg = sigm(v);
                    float th = tanhf_(v);
                    acc[i][jj][r] = (gate == 2) ? th : sg;
                }

        // ---- gather gates to writer lanes (gate==0), update c (regs) & h ----
#pragma unroll
        for (int i = 0; i < 2; i++)
#pragma unroll
            for (int jj = 0; jj < 2; jj++)
#pragma unroll
                for (int r = 0; r < 4; r++) {
                    float nv = acc[i][jj][r];          // i-gate on writer lanes
                    float f1 = __shfl_xor(nv, 1);      // f-gate
                    float f2 = __shfl_xor(nv, 2);      // c-gate (tanh'd)
                    float f3 = __shfl_xor(nv, 3);      // o-gate
                    if (gate == 0) {
                        float cn = f1 * c_reg[i][jj][r] + nv * f2;
                        c_reg[i][jj][r] = cn;
                        float hv = f3 * tanhf_(cn);
                        int row = m0 + wm + i * 16 + lq * 4 + r;
                        int u = (n0 + wn + jj * 16 + lr) >> 2;
                        hs[((size_t)row * T_ + t) * U_ + u] = __float2bfloat16(hv);
                    }
                }

        // ---- group barrier (32 blocks), skip after last step ----
        if (t < T_ - 1) {
            __syncthreads();
            if (tid == 0) {
                __threadfence();
                __hip_atomic_fetch_add(bar + g * 32, 1u, __ATOMIC_RELEASE, __HIP_MEMORY_SCOPE_AGENT);
                unsigned need = 32u * (unsigned)(t + 1);
                while (__hip_atomic_load(bar + g * 32, __ATOMIC_ACQUIRE, __HIP_MEMORY_SCOPE_AGENT) < need)
                    __builtin_amdgcn_s_sleep(2);
                __threadfence();
            }
            __syncthreads();
        }
    }
}

// ---------------------------------------------------------------------------
// dense: out[M,N] = A[M,K](bf16) @ WT[N,K](bf16) + bias ; fp32 out, row-major.
// ---------------------------------------------------------------------------
__global__ __launch_bounds__(256) void gemm_bias(
    const __hip_bfloat16* __restrict__ A, const __hip_bfloat16* __restrict__ WT,
    const float* __restrict__ bias, float* __restrict__ out, int K, int N) {
    const int m0 = blockIdx.x * 128, n0 = blockIdx.y * 64;
    const int tid = threadIdx.x, w = tid >> 6, l = tid & 63, lr = l & 15, lq = l >> 4;
    const int wm = w * 32;

    f32x4 acc[2][4];
#pragma unroll
    for (int jj = 0; jj < 4; jj++) {
        float bv = bias[n0 + jj * 16 + lr];
#pragma unroll
        for (int i = 0; i < 2; i++)
#pragma unroll
            for (int r = 0; r < 4; r++) acc[i][jj][r] = bv;
    }
    for (int k0 = 0; k0 < K; k0 += 32) {
        short8 a[2], b[4];
#pragma unroll
        for (int i = 0; i < 2; i++)
            a[i] = *(const short8*)(A + (size_t)(m0 + wm + i * 16 + lr) * K + k0 + lq * 8);
#pragma unroll
        for (int jj = 0; jj < 4; jj++)
            b[jj] = *(const short8*)(WT + (size_t)(n0 + jj * 16 + lr) * K + k0 + lq * 8);
#pragma unroll
        for (int i = 0; i < 2; i++)
#pragma unroll
            for (int jj = 0; jj < 4; jj++)
                acc[i][jj] = __builtin_amdgcn_mfma_f32_16x16x32_bf16(a[i], b[jj], acc[i][jj], 0, 0, 0);
    }
#pragma unroll
    for (int i = 0; i < 2; i++)
#pragma unroll
        for (int jj = 0; jj < 4; jj++)
#pragma unroll
            for (int r = 0; r < 4; r++)
                out[(size_t)(m0 + wm + i * 16 + lq * 4 + r) * N + n0 + jj * 16 + lr] = acc[i][jj][r];
}

// ---------------------------------------------------------------------------
// reparameterize: z = zm + exp(0.5*zlv)*eps ; also emits exp(zlv) and bf16 z
// ---------------------------------------------------------------------------
__global__ void reparam(const float* __restrict__ zm, const float* __restrict__ zlv,
                        const float* __restrict__ eps, float* __restrict__ z,
                        float* __restrict__ ezlv, __hip_bfloat16* __restrict__ zb, int n) {
    int i = blockIdx.x * 256 + threadIdx.x;
    if (i >= n) return;
    float m = zm[i], lv = zlv[i];
    float zi = m + expf(0.5f * lv) * eps[i];
    z[i] = zi;
    ezlv[i] = expf(lv);
    zb[i] = __float2bfloat16(zi);
}

// ---------------------------------------------------------------------------

extern "C" void kernel_launch(void* const* d_in, const int* in_sizes, int n_in,
                              void* d_out, int out_size, void* d_ws, size_t ws_size,
                              hipStream_t stream) {
    const float* x    = (const float*)d_in[0];
    const float* eps  = (const float*)d_in[1];
    const float* e0Wx = (const float*)d_in[2];
    const float* e0Wh = (const float*)d_in[3];
    const float* e0b  = (const float*)d_in[4];
    const float* e1Wx = (const float*)d_in[5];
    const float* e1Wh = (const float*)d_in[6];
    const float* e1b  = (const float*)d_in[7];
    const float* d0Wx = (const float*)d_in[8];
    const float* d0Wh = (const float*)d_in[9];
    const float* d0b  = (const float*)d_in[10];
    const float* d1Wx = (const float*)d_in[11];
    const float* d1Wh = (const float*)d_in[12];
    const float* d1b  = (const float*)d_in[13];
    const float* Wm   = (const float*)d_in[14];
    const float* bm   = (const float*)d_in[15];
    const float* Wv   = (const float*)d_in[16];
    const float* bv   = (const float*)d_in[17];
    const float* Wo   = (const float*)d_in[18];
    const float* bo   = (const float*)d_in[19];
    float* out = (float*)d_out;

    char* ws = (char*)d_ws;
    size_t off = 0;
    auto alloc = [&](size_t bytes) -> char* {
        off = (off + 255) & ~(size_t)255;
        char* p = ws + off;
        off += bytes;
        return p;
    };
    __hip_bfloat16* hsA  = (__hip_bfloat16*)alloc((size_t)B_ * T_ * U_ * 2); // 64MB
    __hip_bfloat16* hsB  = (__hip_bfloat16*)alloc((size_t)B_ * T_ * U_ * 2); // 64MB
    __hip_bfloat16* xb   = (__hip_bfloat16*)alloc((size_t)B_ * T_ * D_ * 2); // 16MB
    __hip_bfloat16* zb   = (__hip_bfloat16*)alloc((size_t)B_ * T_ * Z_ * 2); //  8MB
    __hip_bfloat16* WTe0 = (__hip_bfloat16*)alloc((size_t)G4_ * (U_ + D_) * 2);
    __hip_bfloat16* WTe1 = (__hip_bfloat16*)alloc((size_t)G4_ * (U_ + U_) * 2);
    __hip_bfloat16* WTd0 = (__hip_bfloat16*)alloc((size_t)G4_ * (U_ + Z_) * 2);
    __hip_bfloat16* WTd1 = (__hip_bfloat16*)alloc((size_t)G4_ * (U_ + U_) * 2);
    __hip_bfloat16* WmT  = (__hip_bfloat16*)alloc((size_t)Z_ * U_ * 2);
    __hip_bfloat16* WvT  = (__hip_bfloat16*)alloc((size_t)Z_ * U_ * 2);
    __hip_bfloat16* WoT  = (__hip_bfloat16*)alloc((size_t)D_ * U_ * 2);
    float* be0 = (float*)alloc(G4_ * 4);
    float* be1 = (float*)alloc(G4_ * 4);
    float* bd0 = (float*)alloc(G4_ * 4);
    float* bd1 = (float*)alloc(G4_ * 4);
    unsigned* bar = (unsigned*)alloc(4 * 8 * 32 * sizeof(unsigned)); // 4 layers x 8 groups x 32-stride

    hipMemsetAsync(bar, 0, 4 * 8 * 32 * sizeof(unsigned), stream);

    // ---- prep: bf16 conversions + weight transpose/permutes ----
    convert_bf16<<<(B_ * T_ * D_ + 255) / 256, 256, 0, stream>>>(x, xb, B_ * T_ * D_);

    auto cw = [&](const float* src, __hip_bfloat16* dst, int K, int Nrows, int Nsrc, int ldd, int koff, int perm) {
        conv_weight<<<(K * Nrows + 255) / 256, 256, 0, stream>>>(src, dst, K, Nrows, Nsrc, ldd, koff, perm);
    };
    cw(e0Wh, WTe0, U_, G4_, G4_, U_ + D_, 0, 1);
    cw(e0Wx, WTe0, D_, G4_, G4_, U_ + D_, U_, 1);
    cw(e1Wh, WTe1, U_, G4_, G4_, U_ + U_, 0, 1);
    cw(e1Wx, WTe1, U_, G4_, G4_, U_ + U_, U_, 1);
    cw(d0Wh, WTd0, U_, G4_, G4_, U_ + Z_, 0, 1);
    cw(d0Wx, WTd0, Z_, G4_, G4_, U_ + Z_, U_, 1);
    cw(d1Wh, WTd1, U_, G4_, G4_, U_ + U_, 0, 1);
    cw(d1Wx, WTd1, U_, G4_, G4_, U_ + U_, U_, 1);
    cw(Wm, WmT, U_, Z_, Z_, U_, 0, 0);
    cw(Wv, WvT, U_, Z_, Z_, U_, 0, 0);
    cw(Wo, WoT, U_, D_, D_, U_, 0, 0);
    conv_bias<<<G4_ / 256, 256, 0, stream>>>(e0b, be0);
    conv_bias<<<G4_ / 256, 256, 0, stream>>>(e1b, be1);
    conv_bias<<<G4_ / 256, 256, 0, stream>>>(d0b, bd0);
    conv_bias<<<G4_ / 256, 256, 0, stream>>>(d1b, bd1);

    // ---- encoder (persistent layers) ----
    lstm_layer_persist<D_><<<256, 256, 0, stream>>>(hsA, xb, WTe0, be0, bar + 0 * 256);
    lstm_layer_persist<U_><<<256, 256, 0, stream>>>(hsB, hsA, WTe1, be1, bar + 1 * 256);

    // ---- latent heads + reparameterize ----
    const size_t oRecon = 0;
    const size_t oE   = (size_t)B_ * T_ * D_;
    const size_t oZm  = oE + (size_t)B_ * T_ * Z_;
    const size_t oZlv = oZm + (size_t)B_ * T_ * Z_;
    const size_t oZ   = oZlv + (size_t)B_ * T_ * Z_;

    gemm_bias<<<dim3(B_ * T_ / 128, Z_ / 64), 256, 0, stream>>>(hsB, WmT, bm, out + oZm, U_, Z_);
    gemm_bias<<<dim3(B_ * T_ / 128, Z_ / 64), 256, 0, stream>>>(hsB, WvT, bv, out + oZlv, U_, Z_);
    reparam<<<(B_ * T_ * Z_ + 255) / 256, 256, 0, stream>>>(out + oZm, out + oZlv, eps,
                                                            out + oZ, out + oE, zb, B_ * T_ * Z_);

    // ---- decoder (persistent layers) ----
    lstm_layer_persist<Z_><<<256, 256, 0, stream>>>(hsA, zb, WTd0, bd0, bar + 2 * 256);
    lstm_layer_persist<U_><<<256, 256, 0, stream>>>(hsB, hsA, WTd1, bd1, bar + 3 * 256);

    // ---- output dense ----
    gemm_bias<<<dim3(B_ * T_ / 128, D_ / 64), 256, 0, stream>>>(hsB, WoT, bo, out + oRecon, U_, D_);
}

// Round 3
// 7344.097 us; speedup vs baseline: 1.8042x; 1.8042x over previous
//
#include <hip/hip_runtime.h>
#include <hip/hip_bf16.h>

// C_VAE_NET: 2-layer LSTM encoder -> reparam -> 2-layer LSTM decoder -> dense.
// B=512, T=128, D=128, Z=64, U=512, gates 4U=2048.
// Round 2: persistent per-layer LSTM kernels with FENCE-FREE group sync.
//  - h exchange via relaxed agent-scope (sc1) atomic u64 load/store: coherent at
//    MALL/L3, no buffer_wbl2/buffer_inv L2 flushes (R1's 28us/step killer).
//  - barrier = relaxed atomic counter, tid0 spin; __syncthreads drains stores.
//  - x-contribution of step t computed BEFORE the barrier wait (overlap).
//  - weights LDS-resident (XOR-swizzled), cell state in registers.

#define B_  512
#define T_  128
#define D_  128
#define Z_  64
#define U_  512
#define G4_ 2048

typedef __attribute__((ext_vector_type(8))) short short8; // 8 x bf16
typedef __attribute__((ext_vector_type(4))) float f32x4;
typedef unsigned long long ull;

__device__ __forceinline__ float tanhf_(float x){ return 2.0f / (1.0f + __expf(-2.0f * x)) - 1.0f; }

// 16B coherent load (two sc1 u64 loads), for h produced by other blocks this kernel
__device__ __forceinline__ short8 ldh16(const __hip_bfloat16* p) {
    const ull* q = (const ull*)p;
    ull a = __hip_atomic_load(q,     __ATOMIC_RELAXED, __HIP_MEMORY_SCOPE_AGENT);
    ull b = __hip_atomic_load(q + 1, __ATOMIC_RELAXED, __HIP_MEMORY_SCOPE_AGENT);
    union { ull u[2]; short8 s; } x;
    x.u[0] = a; x.u[1] = b;
    return x.s;
}

// ---------------------------------------------------------------------------
// prep kernels
// ---------------------------------------------------------------------------

__global__ void convert_bf16(const float* __restrict__ src, __hip_bfloat16* __restrict__ dst, int n) {
    int i = blockIdx.x * 256 + threadIdx.x;
    if (i < n) dst[i] = __float2bfloat16(src[i]);
}

// dst[n][koff+k] = bf16(src[k][pcol(n)]) ; src is [K][Nsrc] row-major fp32.
// perm: pcol = (n&3)*512 + (n>>2)  (gate-interleave i,f,c,o per unit), else n.
__global__ void conv_weight(const float* __restrict__ src, __hip_bfloat16* __restrict__ dst,
                            int K, int Nrows, int Nsrc, int ldd, int koff, int perm) {
    int idx = blockIdx.x * 256 + threadIdx.x;
    if (idx >= K * Nrows) return;
    int n = idx / K, k = idx - n * K;
    int pc = perm ? ((n & 3) * 512 + (n >> 2)) : n;
    dst[(size_t)n * ldd + koff + k] = __float2bfloat16(src[(size_t)k * Nsrc + pc]);
}

__global__ void conv_bias(const float* __restrict__ src, float* __restrict__ dst) {
    int n = blockIdx.x * 256 + threadIdx.x;
    if (n < G4_) dst[n] = src[(n & 3) * 512 + (n >> 2)];
}

// ---------------------------------------------------------------------------
// persistent LSTM layer.
// hs : [B][T][U] bf16 h-sequence (written at [row][t][:] via sc1 atomics)
// xin: [B][T][DIN] bf16 layer input (immutable, cached loads)
// WT : [2048][512+DIN] bf16, row n = permuted gate col; cols = [Wh | Wx]
// bar: per-group counters (stride 32 u32), pre-zeroed
// grid 256 blocks x 256 thr; group g=bid&7 (rows 64g..), ntile j=bid>>3 (cols 64j..)
// ---------------------------------------------------------------------------
template <int DIN>
__global__ __launch_bounds__(256, 1) void lstm_layer_persist(
    __hip_bfloat16* __restrict__ hs,
    const __hip_bfloat16* __restrict__ xin,
    const __hip_bfloat16* __restrict__ WT,
    const float* __restrict__ bias,
    unsigned* __restrict__ bar) {
    constexpr int LDW = U_ + DIN;
    constexpr int S = LDW * 2;                 // LDS row byte stride (mult of 128)
    __shared__ __hip_bfloat16 Wl[64 * LDW];

    const int bid = blockIdx.x;
    const int g = bid & 7;
    const int j = bid >> 3;
    const int m0 = g * 64, n0 = j * 64;
    const int tid = threadIdx.x;
    const int w = tid >> 6, l = tid & 63, lr = l & 15, lq = l >> 4;
    const int wm = (w >> 1) * 32, wn = (w & 1) * 32;
    const int gate = l & 3;
    unsigned* ctr = bar + g * 32;

    // ---- stage weight slice into LDS, XOR-swizzled: byte ^= (row&7)<<4 ----
    constexpr int CH = LDW / 8;
    for (int idx = tid; idx < 64 * CH; idx += 256) {
        int row = idx / CH, ch = idx - row * CH;
        short8 v = *(const short8*)(WT + (size_t)(n0 + row) * LDW + ch * 8);
        int byte = row * S + ((ch * 16) ^ ((row & 7) << 4));
        *(short8*)((char*)Wl + byte) = v;
    }

    const float b0v = bias[n0 + wn + lr];
    const float b1v = bias[n0 + wn + 16 + lr];

    float c_reg[2][2][4];
#pragma unroll
    for (int i = 0; i < 2; i++)
#pragma unroll
        for (int jj = 0; jj < 2; jj++)
#pragma unroll
            for (int r = 0; r < 4; r++) c_reg[i][jj][r] = 0.0f;

    const int rowA0 = m0 + wm + lr, rowA1 = rowA0 + 16;
    const int rB0 = wn + lr, rB1 = wn + 16 + lr;
    const char* WlB0 = (const char*)Wl + rB0 * S;
    const char* WlB1 = (const char*)Wl + rB1 * S;
    const int sw0 = (rB0 & 7) << 4;
    const int sw1 = (rB1 & 7) << 4;
    const int ubase0 = (n0 + wn) >> 2;         // unit base for jj=0 (jj=1: +4)

    __syncthreads();

    for (int t = 0; t < T_; ++t) {
        f32x4 acc[2][2];
#pragma unroll
        for (int i = 0; i < 2; i++)
#pragma unroll
            for (int r = 0; r < 4; r++) { acc[i][0][r] = b0v; acc[i][1][r] = b1v; }

        // ---- x-contribution first: independent of other blocks' step t-1 ----
        {
            const __hip_bfloat16* X0 = xin + ((size_t)rowA0 * T_ + t) * DIN + lq * 8;
            const __hip_bfloat16* X1 = xin + ((size_t)rowA1 * T_ + t) * DIN + lq * 8;
#pragma unroll 4
            for (int k0 = 0; k0 < DIN; k0 += 32) {
                short8 a0 = *(const short8*)(X0 + k0);
                short8 a1 = *(const short8*)(X1 + k0);
                int off = (U_ + k0 + lq * 8) * 2;
                short8 bb0 = *(const short8*)(WlB0 + (off ^ sw0));
                short8 bb1 = *(const short8*)(WlB1 + (off ^ sw1));
                acc[0][0] = __builtin_amdgcn_mfma_f32_16x16x32_bf16(a0, bb0, acc[0][0], 0, 0, 0);
                acc[0][1] = __builtin_amdgcn_mfma_f32_16x16x32_bf16(a0, bb1, acc[0][1], 0, 0, 0);
                acc[1][0] = __builtin_amdgcn_mfma_f32_16x16x32_bf16(a1, bb0, acc[1][0], 0, 0, 0);
                acc[1][1] = __builtin_amdgcn_mfma_f32_16x16x32_bf16(a1, bb1, acc[1][1], 0, 0, 0);
            }
        }

        if (t > 0) {
            // ---- wait: all 32 group blocks finished step t-1 (relaxed spin) ----
            if (tid == 0) {
                unsigned need = 32u * (unsigned)t;
                while (__hip_atomic_load(ctr, __ATOMIC_RELAXED, __HIP_MEMORY_SCOPE_AGENT) < need)
                    __builtin_amdgcn_s_sleep(1);
            }
            __syncthreads();

            // ---- h-contribution: coherent sc1 loads of h(t-1) ----
            const __hip_bfloat16* A0 = hs + ((size_t)rowA0 * T_ + (t - 1)) * U_ + lq * 8;
            const __hip_bfloat16* A1 = hs + ((size_t)rowA1 * T_ + (t - 1)) * U_ + lq * 8;
#pragma unroll 8
            for (int k0 = 0; k0 < U_; k0 += 32) {
                short8 a0 = ldh16(A0 + k0);
                short8 a1 = ldh16(A1 + k0);
                int off = (k0 + lq * 8) * 2;
                short8 bb0 = *(const short8*)(WlB0 + (off ^ sw0));
                short8 bb1 = *(const short8*)(WlB1 + (off ^ sw1));
                acc[0][0] = __builtin_amdgcn_mfma_f32_16x16x32_bf16(a0, bb0, acc[0][0], 0, 0, 0);
                acc[0][1] = __builtin_amdgcn_mfma_f32_16x16x32_bf16(a0, bb1, acc[0][1], 0, 0, 0);
                acc[1][0] = __builtin_amdgcn_mfma_f32_16x16x32_bf16(a1, bb0, acc[1][0], 0, 0, 0);
                acc[1][1] = __builtin_amdgcn_mfma_f32_16x16x32_bf16(a1, bb1, acc[1][1], 0, 0, 0);
            }
        }

        // ---- gates: one exp + one rcp per value (tanh via sigmoid identity) ----
#pragma unroll
        for (int i = 0; i < 2; i++)
#pragma unroll
            for (int jj = 0; jj < 2; jj++) {
#pragma unroll
                for (int r = 0; r < 4; r++) {
                    float v = acc[i][jj][r];
                    float e = __expf((gate == 2) ? -2.0f * v : -v);
                    float s = 1.0f / (1.0f + e);
                    acc[i][jj][r] = (gate == 2) ? 2.0f * s - 1.0f : s;
                }
#pragma unroll
                for (int r = 0; r < 4; r++) {
                    float nv = acc[i][jj][r];          // i-gate on writer lanes
                    float f1 = __shfl_xor(nv, 1);      // f
                    float f2 = __shfl_xor(nv, 2);      // c~ (tanh'd)
                    float f3 = __shfl_xor(nv, 3);      // o
                    unsigned hb = 0;
                    if (gate == 0) {
                        float cn = f1 * c_reg[i][jj][r] + nv * f2;
                        c_reg[i][jj][r] = cn;
                        float hv = f3 * tanhf_(cn);
                        __hip_bfloat16 hbf = __float2bfloat16(hv);
                        unsigned short us;
                        __builtin_memcpy(&us, &hbf, 2);
                        hb = us;
                    }
                    // pack 4 consecutive units (lanes lr=0,4,8,12) into one u64
                    unsigned p  = __shfl_xor(hb, 4);
                    unsigned w2w = hb | (p << 16);
                    unsigned hi = __shfl_xor(w2w, 8);
                    if ((l & 15) == 0) {
                        ull v64 = (ull)w2w | ((ull)hi << 32);
                        int row = m0 + wm + i * 16 + lq * 4 + r;
                        int ub = ubase0 + jj * 4;
                        ull* dst = (ull*)(hs + ((size_t)row * T_ + t) * U_ + ub);
                        __hip_atomic_store(dst, v64, __ATOMIC_RELAXED, __HIP_MEMORY_SCOPE_AGENT);
                    }
                }
            }

        // ---- signal: stores drained by syncthreads' vmcnt, then count up ----
        if (t < T_ - 1) {
            __syncthreads();
            if (tid == 0)
                __hip_atomic_fetch_add(ctr, 1u, __ATOMIC_RELAXED, __HIP_MEMORY_SCOPE_AGENT);
        }
    }
}

// ---------------------------------------------------------------------------
// dense: out[M,N] = A[M,K](bf16) @ WT[N,K](bf16) + bias ; fp32 out, row-major.
// ---------------------------------------------------------------------------
__global__ __launch_bounds__(256) void gemm_bias(
    const __hip_bfloat16* __restrict__ A, const __hip_bfloat16* __restrict__ WT,
    const float* __restrict__ bias, float* __restrict__ out, int K, int N) {
    const int m0 = blockIdx.x * 128, n0 = blockIdx.y * 64;
    const int tid = threadIdx.x, w = tid >> 6, l = tid & 63, lr = l & 15, lq = l >> 4;
    const int wm = w * 32;

    f32x4 acc[2][4];
#pragma unroll
    for (int jj = 0; jj < 4; jj++) {
        float bv = bias[n0 + jj * 16 + lr];
#pragma unroll
        for (int i = 0; i < 2; i++)
#pragma unroll
            for (int r = 0; r < 4; r++) acc[i][jj][r] = bv;
    }
    for (int k0 = 0; k0 < K; k0 += 32) {
        short8 a[2], b[4];
#pragma unroll
        for (int i = 0; i < 2; i++)
            a[i] = *(const short8*)(A + (size_t)(m0 + wm + i * 16 + lr) * K + k0 + lq * 8);
#pragma unroll
        for (int jj = 0; jj < 4; jj++)
            b[jj] = *(const short8*)(WT + (size_t)(n0 + jj * 16 + lr) * K + k0 + lq * 8);
#pragma unroll
        for (int i = 0; i < 2; i++)
#pragma unroll
            for (int jj = 0; jj < 4; jj++)
                acc[i][jj] = __builtin_amdgcn_mfma_f32_16x16x32_bf16(a[i], b[jj], acc[i][jj], 0, 0, 0);
    }
#pragma unroll
    for (int i = 0; i < 2; i++)
#pragma unroll
        for (int jj = 0; jj < 4; jj++)
#pragma unroll
            for (int r = 0; r < 4; r++)
                out[(size_t)(m0 + wm + i * 16 + lq * 4 + r) * N + n0 + jj * 16 + lr] = acc[i][jj][r];
}

// ---------------------------------------------------------------------------
// reparameterize: z = zm + exp(0.5*zlv)*eps ; also emits exp(zlv) and bf16 z
// ---------------------------------------------------------------------------
__global__ void reparam(const float* __restrict__ zm, const float* __restrict__ zlv,
                        const float* __restrict__ eps, float* __restrict__ z,
                        float* __restrict__ ezlv, __hip_bfloat16* __restrict__ zb, int n) {
    int i = blockIdx.x * 256 + threadIdx.x;
    if (i >= n) return;
    float m = zm[i], lv = zlv[i];
    float zi = m + expf(0.5f * lv) * eps[i];
    z[i] = zi;
    ezlv[i] = expf(lv);
    zb[i] = __float2bfloat16(zi);
}

// ---------------------------------------------------------------------------

extern "C" void kernel_launch(void* const* d_in, const int* in_sizes, int n_in,
                              void* d_out, int out_size, void* d_ws, size_t ws_size,
                              hipStream_t stream) {
    const float* x    = (const float*)d_in[0];
    const float* eps  = (const float*)d_in[1];
    const float* e0Wx = (const float*)d_in[2];
    const float* e0Wh = (const float*)d_in[3];
    const float* e0b  = (const float*)d_in[4];
    const float* e1Wx = (const float*)d_in[5];
    const float* e1Wh = (const float*)d_in[6];
    const float* e1b  = (const float*)d_in[7];
    const float* d0Wx = (const float*)d_in[8];
    const float* d0Wh = (const float*)d_in[9];
    const float* d0b  = (const float*)d_in[10];
    const float* d1Wx = (const float*)d_in[11];
    const float* d1Wh = (const float*)d_in[12];
    const float* d1b  = (const float*)d_in[13];
    const float* Wm   = (const float*)d_in[14];
    const float* bm   = (const float*)d_in[15];
    const float* Wv   = (const float*)d_in[16];
    const float* bv   = (const float*)d_in[17];
    const float* Wo   = (const float*)d_in[18];
    const float* bo   = (const float*)d_in[19];
    float* out = (float*)d_out;

    char* ws = (char*)d_ws;
    size_t off = 0;
    auto alloc = [&](size_t bytes) -> char* {
        off = (off + 255) & ~(size_t)255;
        char* p = ws + off;
        off += bytes;
        return p;
    };
    __hip_bfloat16* hsA  = (__hip_bfloat16*)alloc((size_t)B_ * T_ * U_ * 2); // 64MB
    __hip_bfloat16* hsB  = (__hip_bfloat16*)alloc((size_t)B_ * T_ * U_ * 2); // 64MB
    __hip_bfloat16* xb   = (__hip_bfloat16*)alloc((size_t)B_ * T_ * D_ * 2); // 16MB
    __hip_bfloat16* zb   = (__hip_bfloat16*)alloc((size_t)B_ * T_ * Z_ * 2); //  8MB
    __hip_bfloat16* WTe0 = (__hip_bfloat16*)alloc((size_t)G4_ * (U_ + D_) * 2);
    __hip_bfloat16* WTe1 = (__hip_bfloat16*)alloc((size_t)G4_ * (U_ + U_) * 2);
    __hip_bfloat16* WTd0 = (__hip_bfloat16*)alloc((size_t)G4_ * (U_ + Z_) * 2);
    __hip_bfloat16* WTd1 = (__hip_bfloat16*)alloc((size_t)G4_ * (U_ + U_) * 2);
    __hip_bfloat16* WmT  = (__hip_bfloat16*)alloc((size_t)Z_ * U_ * 2);
    __hip_bfloat16* WvT  = (__hip_bfloat16*)alloc((size_t)Z_ * U_ * 2);
    __hip_bfloat16* WoT  = (__hip_bfloat16*)alloc((size_t)D_ * U_ * 2);
    float* be0 = (float*)alloc(G4_ * 4);
    float* be1 = (float*)alloc(G4_ * 4);
    float* bd0 = (float*)alloc(G4_ * 4);
    float* bd1 = (float*)alloc(G4_ * 4);
    unsigned* bar = (unsigned*)alloc(4 * 8 * 32 * sizeof(unsigned)); // 4 layers x 8 groups x stride32

    hipMemsetAsync(bar, 0, 4 * 8 * 32 * sizeof(unsigned), stream);

    // ---- prep: bf16 conversions + weight transpose/permutes ----
    convert_bf16<<<(B_ * T_ * D_ + 255) / 256, 256, 0, stream>>>(x, xb, B_ * T_ * D_);

    auto cw = [&](const float* src, __hip_bfloat16* dst, int K, int Nrows, int Nsrc, int ldd, int koff, int perm) {
        conv_weight<<<(K * Nrows + 255) / 256, 256, 0, stream>>>(src, dst, K, Nrows, Nsrc, ldd, koff, perm);
    };
    cw(e0Wh, WTe0, U_, G4_, G4_, U_ + D_, 0, 1);
    cw(e0Wx, WTe0, D_, G4_, G4_, U_ + D_, U_, 1);
    cw(e1Wh, WTe1, U_, G4_, G4_, U_ + U_, 0, 1);
    cw(e1Wx, WTe1, U_, G4_, G4_, U_ + U_, U_, 1);
    cw(d0Wh, WTd0, U_, G4_, G4_, U_ + Z_, 0, 1);
    cw(d0Wx, WTd0, Z_, G4_, G4_, U_ + Z_, U_, 1);
    cw(d1Wh, WTd1, U_, G4_, G4_, U_ + U_, 0, 1);
    cw(d1Wx, WTd1, U_, G4_, G4_, U_ + U_, U_, 1);
    cw(Wm, WmT, U_, Z_, Z_, U_, 0, 0);
    cw(Wv, WvT, U_, Z_, Z_, U_, 0, 0);
    cw(Wo, WoT, U_, D_, D_, U_, 0, 0);
    conv_bias<<<G4_ / 256, 256, 0, stream>>>(e0b, be0);
    conv_bias<<<G4_ / 256, 256, 0, stream>>>(e1b, be1);
    conv_bias<<<G4_ / 256, 256, 0, stream>>>(d0b, bd0);
    conv_bias<<<G4_ / 256, 256, 0, stream>>>(d1b, bd1);

    // ---- encoder (persistent layers) ----
    lstm_layer_persist<D_><<<256, 256, 0, stream>>>(hsA, xb, WTe0, be0, bar + 0 * 256);
    lstm_layer_persist<U_><<<256, 256, 0, stream>>>(hsB, hsA, WTe1, be1, bar + 1 * 256);

    // ---- latent heads + reparameterize ----
    const size_t oRecon = 0;
    const size_t oE   = (size_t)B_ * T_ * D_;
    const size_t oZm  = oE + (size_t)B_ * T_ * Z_;
    const size_t oZlv = oZm + (size_t)B_ * T_ * Z_;
    const size_t oZ   = oZlv + (size_t)B_ * T_ * Z_;

    gemm_bias<<<dim3(B_ * T_ / 128, Z_ / 64), 256, 0, stream>>>(hsB, WmT, bm, out + oZm, U_, Z_);
    gemm_bias<<<dim3(B_ * T_ / 128, Z_ / 64), 256, 0, stream>>>(hsB, WvT, bv, out + oZlv, U_, Z_);
    reparam<<<(B_ * T_ * Z_ + 255) / 256, 256, 0, stream>>>(out + oZm, out + oZlv, eps,
                                                            out + oZ, out + oE, zb, B_ * T_ * Z_);

    // ---- decoder (persistent layers) ----
    lstm_layer_persist<Z_><<<256, 256, 0, stream>>>(hsA, zb, WTd0, bd0, bar + 2 * 256);
    lstm_layer_persist<U_><<<256, 256, 0, stream>>>(hsB, hsA, WTd1, bd1, bar + 3 * 256);

    // ---- output dense ----
    gemm_bias<<<dim3(B_ * T_ / 128, D_ / 64), 256, 0, stream>>>(hsB, WoT, bo, out + oRecon, U_, D_);
}

// Round 4
// 6818.442 us; speedup vs baseline: 1.9433x; 1.0771x over previous
//
#include <hip/hip_runtime.h>
#include <hip/hip_bf16.h>

// C_VAE_NET: 2-layer LSTM encoder -> reparam -> 2-layer LSTM decoder -> dense.
// B=512, T=128, D=128, Z=64, U=512, gates 4U=2048.
// Round 3: persistent LSTM layers, refined sync + memory layout.
//  - activations in [T][B][U] layout: h(t) is a contiguous 512KB slab.
//  - h written via LDS-staged COALESCED sc1 u64 stores (no 4x write amplification).
//  - barrier = per-block padded flag array (no atomic RMW, parallel 32-lane poll).
//  - x-contribution computed before the wait; weights LDS-resident (XOR-swizzled);
//    cell state in registers.

#define B_  512
#define T_  128
#define D_  128
#define Z_  64
#define U_  512
#define G4_ 2048

typedef __attribute__((ext_vector_type(8))) short short8; // 8 x bf16
typedef __attribute__((ext_vector_type(4))) float f32x4;
typedef unsigned long long ull;

__device__ __forceinline__ float tanhf_(float x){ return 2.0f / (1.0f + __expf(-2.0f * x)) - 1.0f; }

// 16B coherent load (two sc1 u64 loads) for intra-kernel cross-block h
__device__ __forceinline__ short8 ldh16(const __hip_bfloat16* p) {
    const ull* q = (const ull*)p;
    ull a = __hip_atomic_load(q,     __ATOMIC_RELAXED, __HIP_MEMORY_SCOPE_AGENT);
    ull b = __hip_atomic_load(q + 1, __ATOMIC_RELAXED, __HIP_MEMORY_SCOPE_AGENT);
    union { ull u[2]; short8 s; } x;
    x.u[0] = a; x.u[1] = b;
    return x.s;
}

// ---------------------------------------------------------------------------
// prep kernels
// ---------------------------------------------------------------------------

// x [B][T][D] fp32 -> xb [T][B][D] bf16
__global__ void convert_transpose(const float* __restrict__ src, __hip_bfloat16* __restrict__ dst) {
    int i = blockIdx.x * 256 + threadIdx.x;          // dst-linear over T*B*D
    if (i >= B_ * T_ * D_) return;
    int t = i >> 16;                                  // /(B*D)=65536
    int rem = i & 65535;
    int b = rem >> 7, d = rem & 127;                  // D=128
    dst[i] = __float2bfloat16(src[((size_t)b * T_ + t) * D_ + d]);
}

// dst[n][koff+k] = bf16(src[k][pcol(n)]) ; src is [K][Nsrc] row-major fp32.
// perm: pcol = (n&3)*512 + (n>>2)  (gate-interleave i,f,c,o per unit), else n.
__global__ void conv_weight(const float* __restrict__ src, __hip_bfloat16* __restrict__ dst,
                            int K, int Nrows, int Nsrc, int ldd, int koff, int perm) {
    int idx = blockIdx.x * 256 + threadIdx.x;
    if (idx >= K * Nrows) return;
    int n = idx / K, k = idx - n * K;
    int pc = perm ? ((n & 3) * 512 + (n >> 2)) : n;
    dst[(size_t)n * ldd + koff + k] = __float2bfloat16(src[(size_t)k * Nsrc + pc]);
}

__global__ void conv_bias(const float* __restrict__ src, float* __restrict__ dst) {
    int n = blockIdx.x * 256 + threadIdx.x;
    if (n < G4_) dst[n] = src[(n & 3) * 512 + (n >> 2)];
}

// ---------------------------------------------------------------------------
// persistent LSTM layer.
// hs : [T][B][U] bf16 h-sequence (step-t slab written via coalesced sc1 stores)
// xin: [T][B][DIN] bf16 layer input (plain cached loads; cross-dispatch coherent)
// WT : [2048][512+DIN] bf16, row n = permuted gate col; cols = [Wh | Wx]
// flags: [8 groups][32 members][16 u32] (64B-padded), pre-zeroed
// grid 256 blocks x 256 thr; group g=bid&7 (rows 64g..), ntile j=bid>>3 (cols 64j..)
// ---------------------------------------------------------------------------
template <int DIN>
__global__ __launch_bounds__(256, 1) void lstm_layer_persist(
    __hip_bfloat16* __restrict__ hs,
    const __hip_bfloat16* __restrict__ xin,
    const __hip_bfloat16* __restrict__ WT,
    const float* __restrict__ bias,
    unsigned* __restrict__ flags) {
    constexpr int LDW = U_ + DIN;
    constexpr int S = LDW * 2;                  // LDS row byte stride (mult of 128)
    __shared__ __hip_bfloat16 Wl[64 * LDW];
    __shared__ __hip_bfloat16 hstage[64 * 16];  // block's h output tile [row][unit]

    const int bid = blockIdx.x;
    const int g = bid & 7;
    const int j = bid >> 3;
    const int m0 = g * 64, n0 = j * 64;
    const int tid = threadIdx.x;
    const int w = tid >> 6, l = tid & 63, lr = l & 15, lq = l >> 4;
    const int wm = (w >> 1) * 32, wn = (w & 1) * 32;
    const int gate = l & 3;
    unsigned* gflags = flags + g * (32 * 16);
    unsigned* myflag = gflags + j * 16;

    // ---- stage weight slice into LDS, XOR-swizzled: byte ^= (row&7)<<4 ----
    constexpr int CH = LDW / 8;
    for (int idx = tid; idx < 64 * CH; idx += 256) {
        int row = idx / CH, ch = idx - row * CH;
        short8 v = *(const short8*)(WT + (size_t)(n0 + row) * LDW + ch * 8);
        int byte = row * S + ((ch * 16) ^ ((row & 7) << 4));
        *(short8*)((char*)Wl + byte) = v;
    }

    const float b0v = bias[n0 + wn + lr];
    const float b1v = bias[n0 + wn + 16 + lr];

    float c_reg[2][2][4];
#pragma unroll
    for (int i = 0; i < 2; i++)
#pragma unroll
        for (int jj = 0; jj < 2; jj++)
#pragma unroll
            for (int r = 0; r < 4; r++) c_reg[i][jj][r] = 0.0f;

    const int rowA0 = m0 + wm + lr, rowA1 = rowA0 + 16;
    const int rB0 = wn + lr, rB1 = wn + 16 + lr;
    const char* WlB0 = (const char*)Wl + rB0 * S;
    const char* WlB1 = (const char*)Wl + rB1 * S;
    const int sw0 = (rB0 & 7) << 4;
    const int sw1 = (rB1 & 7) << 4;

    __syncthreads();

    for (int t = 0; t < T_; ++t) {
        f32x4 acc[2][2];
#pragma unroll
        for (int i = 0; i < 2; i++)
#pragma unroll
            for (int r = 0; r < 4; r++) { acc[i][0][r] = b0v; acc[i][1][r] = b1v; }

        // ---- x-contribution first: independent of other blocks' step t-1 ----
        {
            const __hip_bfloat16* X0 = xin + ((size_t)t * B_ + rowA0) * DIN + lq * 8;
            const __hip_bfloat16* X1 = xin + ((size_t)t * B_ + rowA1) * DIN + lq * 8;
#pragma unroll 4
            for (int k0 = 0; k0 < DIN; k0 += 32) {
                short8 a0 = *(const short8*)(X0 + k0);
                short8 a1 = *(const short8*)(X1 + k0);
                int off = (U_ + k0 + lq * 8) * 2;
                short8 bb0 = *(const short8*)(WlB0 + (off ^ sw0));
                short8 bb1 = *(const short8*)(WlB1 + (off ^ sw1));
                acc[0][0] = __builtin_amdgcn_mfma_f32_16x16x32_bf16(a0, bb0, acc[0][0], 0, 0, 0);
                acc[0][1] = __builtin_amdgcn_mfma_f32_16x16x32_bf16(a0, bb1, acc[0][1], 0, 0, 0);
                acc[1][0] = __builtin_amdgcn_mfma_f32_16x16x32_bf16(a1, bb0, acc[1][0], 0, 0, 0);
                acc[1][1] = __builtin_amdgcn_mfma_f32_16x16x32_bf16(a1, bb1, acc[1][1], 0, 0, 0);
            }
        }

        if (t > 0) {
            // ---- wait: every group block set flag >= t (parallel poll, no RMW) ----
            if (tid < 32) {
                const unsigned* f = gflags + tid * 16;
                unsigned need = (unsigned)t;
                while (__hip_atomic_load(f, __ATOMIC_RELAXED, __HIP_MEMORY_SCOPE_AGENT) < need)
                    __builtin_amdgcn_s_sleep(1);
            }
            __syncthreads();

            // ---- h-contribution: coherent sc1 loads of the h(t-1) slab ----
            const __hip_bfloat16* A0 = hs + ((size_t)(t - 1) * B_ + rowA0) * U_ + lq * 8;
            const __hip_bfloat16* A1 = hs + ((size_t)(t - 1) * B_ + rowA1) * U_ + lq * 8;
#pragma unroll 8
            for (int k0 = 0; k0 < U_; k0 += 32) {
                short8 a0 = ldh16(A0 + k0);
                short8 a1 = ldh16(A1 + k0);
                int off = (k0 + lq * 8) * 2;
                short8 bb0 = *(const short8*)(WlB0 + (off ^ sw0));
                short8 bb1 = *(const short8*)(WlB1 + (off ^ sw1));
                acc[0][0] = __builtin_amdgcn_mfma_f32_16x16x32_bf16(a0, bb0, acc[0][0], 0, 0, 0);
                acc[0][1] = __builtin_amdgcn_mfma_f32_16x16x32_bf16(a0, bb1, acc[0][1], 0, 0, 0);
                acc[1][0] = __builtin_amdgcn_mfma_f32_16x16x32_bf16(a1, bb0, acc[1][0], 0, 0, 0);
                acc[1][1] = __builtin_amdgcn_mfma_f32_16x16x32_bf16(a1, bb1, acc[1][1], 0, 0, 0);
            }
        }

        // ---- gates: one exp + one rcp per value; writers update c, stage h ----
#pragma unroll
        for (int i = 0; i < 2; i++)
#pragma unroll
            for (int jj = 0; jj < 2; jj++) {
#pragma unroll
                for (int r = 0; r < 4; r++) {
                    float v = acc[i][jj][r];
                    float e = __expf((gate == 2) ? -2.0f * v : -v);
                    float s = 1.0f / (1.0f + e);
                    acc[i][jj][r] = (gate == 2) ? 2.0f * s - 1.0f : s;
                }
#pragma unroll
                for (int r = 0; r < 4; r++) {
                    float nv = acc[i][jj][r];          // i-gate on writer lanes
                    float f1 = __shfl_xor(nv, 1);      // f
                    float f2 = __shfl_xor(nv, 2);      // c~ (tanh'd)
                    float f3 = __shfl_xor(nv, 3);      // o
                    if (gate == 0) {
                        float cn = f1 * c_reg[i][jj][r] + nv * f2;
                        c_reg[i][jj][r] = cn;
                        float hv = f3 * tanhf_(cn);
                        int lrow = wm + i * 16 + lq * 4 + r;          // 0..63
                        int lu = (wn + jj * 16 + lr) >> 2;            // 0..15
                        hstage[lrow * 16 + lu] = __float2bfloat16(hv);
                    }
                }
            }

        __syncthreads();   // hstage complete

        // ---- coalesced h store: 128 threads x 16B consecutive, sc1 ----
        if (tid < 128) {
            int lrow = tid >> 1, half = tid & 1;
            union { short8 s; ull u[2]; } X;
            X.s = *(const short8*)(hstage + lrow * 16 + half * 8);
            ull* dst = (ull*)(hs + ((size_t)t * B_ + m0 + lrow) * U_ + j * 16 + half * 8);
            __hip_atomic_store(dst,     X.u[0], __ATOMIC_RELAXED, __HIP_MEMORY_SCOPE_AGENT);
            __hip_atomic_store(dst + 1, X.u[1], __ATOMIC_RELAXED, __HIP_MEMORY_SCOPE_AGENT);
        }

        // ---- signal: syncthreads drains vmcnt (stores acked at L3), then flag ----
        if (t < T_ - 1) {
            __syncthreads();
            if (tid == 0)
                __hip_atomic_store(myflag, (unsigned)(t + 1), __ATOMIC_RELAXED, __HIP_MEMORY_SCOPE_AGENT);
        }
    }
}

// ---------------------------------------------------------------------------
// dense: out[M,N] = A[M,K](bf16,[T][B] rows) @ WT[N,K](bf16) + bias ;
// fp32 out written in harness [B][T] row order.
// ---------------------------------------------------------------------------
__global__ __launch_bounds__(256) void gemm_bias(
    const __hip_bfloat16* __restrict__ A, const __hip_bfloat16* __restrict__ WT,
    const float* __restrict__ bias, float* __restrict__ out, int K, int N) {
    const int m0 = blockIdx.x * 128, n0 = blockIdx.y * 64;
    const int tid = threadIdx.x, w = tid >> 6, l = tid & 63, lr = l & 15, lq = l >> 4;
    const int wm = w * 32;

    f32x4 acc[2][4];
#pragma unroll
    for (int jj = 0; jj < 4; jj++) {
        float bv = bias[n0 + jj * 16 + lr];
#pragma unroll
        for (int i = 0; i < 2; i++)
#pragma unroll
            for (int r = 0; r < 4; r++) acc[i][jj][r] = bv;
    }
    for (int k0 = 0; k0 < K; k0 += 32) {
        short8 a[2], b[4];
#pragma unroll
        for (int i = 0; i < 2; i++)
            a[i] = *(const short8*)(A + (size_t)(m0 + wm + i * 16 + lr) * K + k0 + lq * 8);
#pragma unroll
        for (int jj = 0; jj < 4; jj++)
            b[jj] = *(const short8*)(WT + (size_t)(n0 + jj * 16 + lr) * K + k0 + lq * 8);
#pragma unroll
        for (int i = 0; i < 2; i++)
#pragma unroll
            for (int jj = 0; jj < 4; jj++)
                acc[i][jj] = __builtin_amdgcn_mfma_f32_16x16x32_bf16(a[i], b[jj], acc[i][jj], 0, 0, 0);
    }
#pragma unroll
    for (int i = 0; i < 2; i++)
#pragma unroll
        for (int jj = 0; jj < 4; jj++)
#pragma unroll
            for (int r = 0; r < 4; r++) {
                int ra = m0 + wm + i * 16 + lq * 4 + r;     // = t*512 + b
                int rh = (ra & 511) * T_ + (ra >> 9);       // = b*T + t
                out[(size_t)rh * N + n0 + jj * 16 + lr] = acc[i][jj][r];
            }
}

// ---------------------------------------------------------------------------
// reparameterize: z = zm + exp(0.5*zlv)*eps (harness [B][T][Z] order);
// also emits exp(zlv) and bf16 z in [T][B][Z] layout for the decoder.
// ---------------------------------------------------------------------------
__global__ void reparam(const float* __restrict__ zm, const float* __restrict__ zlv,
                        const float* __restrict__ eps, float* __restrict__ z,
                        float* __restrict__ ezlv, __hip_bfloat16* __restrict__ zb, int n) {
    int i = blockIdx.x * 256 + threadIdx.x;
    if (i >= n) return;
    float m = zm[i], lv = zlv[i];
    float zi = m + expf(0.5f * lv) * eps[i];
    z[i] = zi;
    ezlv[i] = expf(lv);
    int b = i >> 13;                       // /(T*Z)=8192
    int rem = i & 8191;
    int t = rem >> 6, zc = rem & 63;       // Z=64
    zb[(((size_t)t << 9) + b) * Z_ + zc] = __float2bfloat16(zi);
}

// ---------------------------------------------------------------------------

extern "C" void kernel_launch(void* const* d_in, const int* in_sizes, int n_in,
                              void* d_out, int out_size, void* d_ws, size_t ws_size,
                              hipStream_t stream) {
    const float* x    = (const float*)d_in[0];
    const float* eps  = (const float*)d_in[1];
    const float* e0Wx = (const float*)d_in[2];
    const float* e0Wh = (const float*)d_in[3];
    const float* e0b  = (const float*)d_in[4];
    const float* e1Wx = (const float*)d_in[5];
    const float* e1Wh = (const float*)d_in[6];
    const float* e1b  = (const float*)d_in[7];
    const float* d0Wx = (const float*)d_in[8];
    const float* d0Wh = (const float*)d_in[9];
    const float* d0b  = (const float*)d_in[10];
    const float* d1Wx = (const float*)d_in[11];
    const float* d1Wh = (const float*)d_in[12];
    const float* d1b  = (const float*)d_in[13];
    const float* Wm   = (const float*)d_in[14];
    const float* bm   = (const float*)d_in[15];
    const float* Wv   = (const float*)d_in[16];
    const float* bv   = (const float*)d_in[17];
    const float* Wo   = (const float*)d_in[18];
    const float* bo   = (const float*)d_in[19];
    float* out = (float*)d_out;

    char* ws = (char*)d_ws;
    size_t off = 0;
    auto alloc = [&](size_t bytes) -> char* {
        off = (off + 255) & ~(size_t)255;
        char* p = ws + off;
        off += bytes;
        return p;
    };
    __hip_bfloat16* hsA  = (__hip_bfloat16*)alloc((size_t)B_ * T_ * U_ * 2); // 64MB, [T][B][U]
    __hip_bfloat16* hsB  = (__hip_bfloat16*)alloc((size_t)B_ * T_ * U_ * 2); // 64MB, [T][B][U]
    __hip_bfloat16* xb   = (__hip_bfloat16*)alloc((size_t)B_ * T_ * D_ * 2); // 16MB, [T][B][D]
    __hip_bfloat16* zb   = (__hip_bfloat16*)alloc((size_t)B_ * T_ * Z_ * 2); //  8MB, [T][B][Z]
    __hip_bfloat16* WTe0 = (__hip_bfloat16*)alloc((size_t)G4_ * (U_ + D_) * 2);
    __hip_bfloat16* WTe1 = (__hip_bfloat16*)alloc((size_t)G4_ * (U_ + U_) * 2);
    __hip_bfloat16* WTd0 = (__hip_bfloat16*)alloc((size_t)G4_ * (U_ + Z_) * 2);
    __hip_bfloat16* WTd1 = (__hip_bfloat16*)alloc((size_t)G4_ * (U_ + U_) * 2);
    __hip_bfloat16* WmT  = (__hip_bfloat16*)alloc((size_t)Z_ * U_ * 2);
    __hip_bfloat16* WvT  = (__hip_bfloat16*)alloc((size_t)Z_ * U_ * 2);
    __hip_bfloat16* WoT  = (__hip_bfloat16*)alloc((size_t)D_ * U_ * 2);
    float* be0 = (float*)alloc(G4_ * 4);
    float* be1 = (float*)alloc(G4_ * 4);
    float* bd0 = (float*)alloc(G4_ * 4);
    float* bd1 = (float*)alloc(G4_ * 4);
    unsigned* flags = (unsigned*)alloc(4 * 8 * 32 * 16 * sizeof(unsigned)); // 64KB, 64B-padded

    hipMemsetAsync(flags, 0, 4 * 8 * 32 * 16 * sizeof(unsigned), stream);

    // ---- prep: bf16 conversions + weight transpose/permutes ----
    convert_transpose<<<(B_ * T_ * D_ + 255) / 256, 256, 0, stream>>>(x, xb);

    auto cw = [&](const float* src, __hip_bfloat16* dst, int K, int Nrows, int Nsrc, int ldd, int koff, int perm) {
        conv_weight<<<(K * Nrows + 255) / 256, 256, 0, stream>>>(src, dst, K, Nrows, Nsrc, ldd, koff, perm);
    };
    cw(e0Wh, WTe0, U_, G4_, G4_, U_ + D_, 0, 1);
    cw(e0Wx, WTe0, D_, G4_, G4_, U_ + D_, U_, 1);
    cw(e1Wh, WTe1, U_, G4_, G4_, U_ + U_, 0, 1);
    cw(e1Wx, WTe1, U_, G4_, G4_, U_ + U_, U_, 1);
    cw(d0Wh, WTd0, U_, G4_, G4_, U_ + Z_, 0, 1);
    cw(d0Wx, WTd0, Z_, G4_, G4_, U_ + Z_, U_, 1);
    cw(d1Wh, WTd1, U_, G4_, G4_, U_ + U_, 0, 1);
    cw(d1Wx, WTd1, U_, G4_, G4_, U_ + U_, U_, 1);
    cw(Wm, WmT, U_, Z_, Z_, U_, 0, 0);
    cw(Wv, WvT, U_, Z_, Z_, U_, 0, 0);
    cw(Wo, WoT, U_, D_, D_, U_, 0, 0);
    conv_bias<<<G4_ / 256, 256, 0, stream>>>(e0b, be0);
    conv_bias<<<G4_ / 256, 256, 0, stream>>>(e1b, be1);
    conv_bias<<<G4_ / 256, 256, 0, stream>>>(d0b, bd0);
    conv_bias<<<G4_ / 256, 256, 0, stream>>>(d1b, bd1);

    // ---- encoder (persistent layers) ----
    lstm_layer_persist<D_><<<256, 256, 0, stream>>>(hsA, xb, WTe0, be0, flags + 0 * 4096);
    lstm_layer_persist<U_><<<256, 256, 0, stream>>>(hsB, hsA, WTe1, be1, flags + 1 * 4096);

    // ---- latent heads + reparameterize ----
    const size_t oRecon = 0;
    const size_t oE   = (size_t)B_ * T_ * D_;
    const size_t oZm  = oE + (size_t)B_ * T_ * Z_;
    const size_t oZlv = oZm + (size_t)B_ * T_ * Z_;
    const size_t oZ   = oZlv + (size_t)B_ * T_ * Z_;

    gemm_bias<<<dim3(B_ * T_ / 128, Z_ / 64), 256, 0, stream>>>(hsB, WmT, bm, out + oZm, U_, Z_);
    gemm_bias<<<dim3(B_ * T_ / 128, Z_ / 64), 256, 0, stream>>>(hsB, WvT, bv, out + oZlv, U_, Z_);
    reparam<<<(B_ * T_ * Z_ + 255) / 256, 256, 0, stream>>>(out + oZm, out + oZlv, eps,
                                                            out + oZ, out + oE, zb, B_ * T_ * Z_);

    // ---- decoder (persistent layers) ----
    lstm_layer_persist<Z_><<<256, 256, 0, stream>>>(hsA, zb, WTd0, bd0, flags + 2 * 4096);
    lstm_layer_persist<U_><<<256, 256, 0, stream>>>(hsB, hsA, WTd1, bd1, flags + 3 * 4096);

    // ---- output dense ----
    gemm_bias<<<dim3(B_ * T_ / 128, D_ / 64), 256, 0, stream>>>(hsB, WoT, bo, out + oRecon, U_, D_);
}

// Round 5
// 4389.234 us; speedup vs baseline: 3.0188x; 1.5534x over previous
//
#include <hip/hip_runtime.h>
#include <hip/hip_bf16.h>

// C_VAE_NET: 2-layer LSTM encoder -> reparam -> 2-layer LSTM decoder -> dense.
// B=512, T=128, D=128, Z=64, U=512, gates 4U=2048.
// Round 4: kill the h-load latency serialization.
//  - h(t-1) staged into LDS once per step via a cooperative BURST of sc1 atomic
//    loads (one ~800cy latency wall, not 16 serialized round trips).
//  - h-MFMA loop runs from LDS (swizzled ds_read_b128, compiler-pipelined).
//  - Wh LDS-resident; Wx LDS-resident for DIN<=128, L2-streamed for DIN=512.
//  - [T][B][U] layout, coalesced sc1 h-stores, flag-array barrier (R3).

#define B_  512
#define T_  128
#define D_  128
#define Z_  64
#define U_  512
#define G4_ 2048

typedef __attribute__((ext_vector_type(8))) short short8; // 8 x bf16
typedef __attribute__((ext_vector_type(4))) float f32x4;
typedef unsigned long long ull;

__device__ __forceinline__ float tanhf_(float x){ return 2.0f / (1.0f + __expf(-2.0f * x)) - 1.0f; }

// ---------------------------------------------------------------------------
// prep kernels
// ---------------------------------------------------------------------------

// x [B][T][D] fp32 -> xb [T][B][D] bf16
__global__ void convert_transpose(const float* __restrict__ src, __hip_bfloat16* __restrict__ dst) {
    int i = blockIdx.x * 256 + threadIdx.x;          // dst-linear over T*B*D
    if (i >= B_ * T_ * D_) return;
    int t = i >> 16;                                  // /(B*D)=65536
    int rem = i & 65535;
    int b = rem >> 7, d = rem & 127;                  // D=128
    dst[i] = __float2bfloat16(src[((size_t)b * T_ + t) * D_ + d]);
}

// dst[n][koff+k] = bf16(src[k][pcol(n)]) ; src is [K][Nsrc] row-major fp32.
// perm: pcol = (n&3)*512 + (n>>2)  (gate-interleave i,f,c,o per unit), else n.
__global__ void conv_weight(const float* __restrict__ src, __hip_bfloat16* __restrict__ dst,
                            int K, int Nrows, int Nsrc, int ldd, int koff, int perm) {
    int idx = blockIdx.x * 256 + threadIdx.x;
    if (idx >= K * Nrows) return;
    int n = idx / K, k = idx - n * K;
    int pc = perm ? ((n & 3) * 512 + (n >> 2)) : n;
    dst[(size_t)n * ldd + koff + k] = __float2bfloat16(src[(size_t)k * Nsrc + pc]);
}

__global__ void conv_bias(const float* __restrict__ src, float* __restrict__ dst) {
    int n = blockIdx.x * 256 + threadIdx.x;
    if (n < G4_) dst[n] = src[(n & 3) * 512 + (n >> 2)];
}

// ---------------------------------------------------------------------------
// persistent LSTM layer.
// hs : [T][B][U] bf16 h-sequence (step-t slab written via coalesced sc1 stores)
// xin: [T][B][DIN] bf16 layer input (plain cached loads)
// WT : [2048][512+DIN] bf16, row n = permuted gate col; cols = [Wh | Wx]
// flags: [8 groups][32 members][16 u32] (64B-padded), pre-zeroed
// grid 256 blocks x 256 thr; group g=bid&7 (rows 64g..), ntile j=bid>>3 (cols 64j..)
// ---------------------------------------------------------------------------
template <int DIN>
__global__ __launch_bounds__(256, 1) void lstm_layer_persist(
    __hip_bfloat16* __restrict__ hs,
    const __hip_bfloat16* __restrict__ xin,
    const __hip_bfloat16* __restrict__ WT,
    const float* __restrict__ bias,
    unsigned* __restrict__ flags) {
    constexpr bool WX_LDS = (DIN <= 128);
    constexpr int LDW = U_ + DIN;
    constexpr int SX = DIN * 2;                 // Wx LDS row byte stride
    __shared__ __hip_bfloat16 WhL[64 * U_];     // 64KB, swizzled
    __shared__ __hip_bfloat16 hL[64 * U_];      // 64KB, swizzled
    __shared__ __hip_bfloat16 WxL[WX_LDS ? 64 * DIN : 64];
    __shared__ __hip_bfloat16 hstage[64 * 16];  // 2KB

    const int bid = blockIdx.x;
    const int g = bid & 7;
    const int j = bid >> 3;
    const int m0 = g * 64, n0 = j * 64;
    const int tid = threadIdx.x;
    const int w = tid >> 6, l = tid & 63, lr = l & 15, lq = l >> 4;
    const int wm = (w >> 1) * 32, wn = (w & 1) * 32;
    const int gate = l & 3;
    unsigned* gflags = flags + g * (32 * 16);
    unsigned* myflag = gflags + j * 16;

    // ---- stage Wh (and Wx if small) into LDS, XOR-swizzled ----
    for (int idx = tid; idx < 64 * 64; idx += 256) {
        int row = idx >> 6, ch = idx & 63;
        short8 v = *(const short8*)(WT + (size_t)(n0 + row) * LDW + ch * 8);
        int byte = row * 1024 + ((ch * 16) ^ ((row & 7) << 4));
        *(short8*)((char*)WhL + byte) = v;
    }
    if constexpr (WX_LDS) {
        constexpr int CHX = DIN / 8;
        for (int idx = tid; idx < 64 * CHX; idx += 256) {
            int row = idx / CHX, ch = idx - row * CHX;
            short8 v = *(const short8*)(WT + (size_t)(n0 + row) * LDW + U_ + ch * 8);
            int byte = row * SX + ((ch * 16) ^ ((row & 7) << 4));
            *(short8*)((char*)WxL + byte) = v;
        }
    }

    const float b0v = bias[n0 + wn + lr];
    const float b1v = bias[n0 + wn + 16 + lr];

    float c_reg[2][2][4];
#pragma unroll
    for (int i = 0; i < 2; i++)
#pragma unroll
        for (int jj = 0; jj < 2; jj++)
#pragma unroll
            for (int r = 0; r < 4; r++) c_reg[i][jj][r] = 0.0f;

    const int rowA0 = m0 + wm + lr, rowA1 = rowA0 + 16;   // global batch rows
    const int lrow0 = wm + lr;                             // local rows in hL
    const int rB0 = wn + lr, rB1 = wn + 16 + lr;
    const int sw = (lr & 7) << 4;                          // shared swizzle (rows == lr mod 8)
    const char* WhB0 = (const char*)WhL + rB0 * 1024;
    const char* WhB1 = (const char*)WhL + rB1 * 1024;
    const char* hA0  = (const char*)hL + lrow0 * 1024;
    const char* hA1  = (const char*)hL + (lrow0 + 16) * 1024;

    __syncthreads();

    for (int t = 0; t < T_; ++t) {
        f32x4 acc[2][2];
#pragma unroll
        for (int i = 0; i < 2; i++)
#pragma unroll
            for (int r = 0; r < 4; r++) { acc[i][0][r] = b0v; acc[i][1][r] = b1v; }

        // ---- x-contribution first: independent of peers' step t-1 ----
        {
            const __hip_bfloat16* X0 = xin + ((size_t)t * B_ + rowA0) * DIN + lq * 8;
            const __hip_bfloat16* X1 = xin + ((size_t)t * B_ + rowA1) * DIN + lq * 8;
#pragma unroll
            for (int k0 = 0; k0 < DIN; k0 += 32) {
                short8 a0 = *(const short8*)(X0 + k0);
                short8 a1 = *(const short8*)(X1 + k0);
                short8 bb0, bb1;
                if constexpr (WX_LDS) {
                    int off = (k0 + lq * 8) * 2;
                    bb0 = *(const short8*)((const char*)WxL + rB0 * SX + (off ^ sw));
                    bb1 = *(const short8*)((const char*)WxL + rB1 * SX + (off ^ sw));
                } else {
                    bb0 = *(const short8*)(WT + (size_t)(n0 + rB0) * LDW + U_ + k0 + lq * 8);
                    bb1 = *(const short8*)(WT + (size_t)(n0 + rB1) * LDW + U_ + k0 + lq * 8);
                }
                acc[0][0] = __builtin_amdgcn_mfma_f32_16x16x32_bf16(a0, bb0, acc[0][0], 0, 0, 0);
                acc[0][1] = __builtin_amdgcn_mfma_f32_16x16x32_bf16(a0, bb1, acc[0][1], 0, 0, 0);
                acc[1][0] = __builtin_amdgcn_mfma_f32_16x16x32_bf16(a1, bb0, acc[1][0], 0, 0, 0);
                acc[1][1] = __builtin_amdgcn_mfma_f32_16x16x32_bf16(a1, bb1, acc[1][1], 0, 0, 0);
            }
        }

        if (t > 0) {
            // ---- wait: every group block set flag >= t (parallel poll, no RMW) ----
            if (tid < 32) {
                const unsigned* f = gflags + tid * 16;
                unsigned need = (unsigned)t;
                while (__hip_atomic_load(f, __ATOMIC_RELAXED, __HIP_MEMORY_SCOPE_AGENT) < need)
                    __builtin_amdgcn_s_sleep(1);
            }
            __syncthreads();

            // ---- BURST-stage h(t-1) slab (64KB) into LDS: all loads in flight ----
            {
                const ull* hsrc = (const ull*)(hs + ((size_t)(t - 1) * B_ + m0) * U_);
                ull r0[16], r1[16];
#pragma unroll
                for (int c = 0; c < 16; c++) {
                    int ci = c * 256 + tid;                    // 16B-chunk index
                    r0[c] = __hip_atomic_load(hsrc + ci * 2,     __ATOMIC_RELAXED, __HIP_MEMORY_SCOPE_AGENT);
                    r1[c] = __hip_atomic_load(hsrc + ci * 2 + 1, __ATOMIC_RELAXED, __HIP_MEMORY_SCOPE_AGENT);
                }
#pragma unroll
                for (int c = 0; c < 16; c++) {
                    int ci = c * 256 + tid;
                    int row = ci >> 6, ch = ci & 63;
                    int byte = row * 1024 + ((ch * 16) ^ ((row & 7) << 4));
                    union { ull u[2]; short8 s; } X;
                    X.u[0] = r0[c]; X.u[1] = r1[c];
                    *(short8*)((char*)hL + byte) = X.s;
                }
            }
            __syncthreads();

            // ---- h-contribution from LDS (swizzled, lgkm-pipelined) ----
#pragma unroll 8
            for (int k0 = 0; k0 < U_; k0 += 32) {
                int off = (k0 + lq * 8) * 2;
                short8 a0 = *(const short8*)(hA0 + (off ^ sw));
                short8 a1 = *(const short8*)(hA1 + (off ^ sw));
                short8 bb0 = *(const short8*)(WhB0 + (off ^ sw));
                short8 bb1 = *(const short8*)(WhB1 + (off ^ sw));
                acc[0][0] = __builtin_amdgcn_mfma_f32_16x16x32_bf16(a0, bb0, acc[0][0], 0, 0, 0);
                acc[0][1] = __builtin_amdgcn_mfma_f32_16x16x32_bf16(a0, bb1, acc[0][1], 0, 0, 0);
                acc[1][0] = __builtin_amdgcn_mfma_f32_16x16x32_bf16(a1, bb0, acc[1][0], 0, 0, 0);
                acc[1][1] = __builtin_amdgcn_mfma_f32_16x16x32_bf16(a1, bb1, acc[1][1], 0, 0, 0);
            }
        }

        // ---- gates: one exp + one rcp per value; writers update c, stage h ----
#pragma unroll
        for (int i = 0; i < 2; i++)
#pragma unroll
            for (int jj = 0; jj < 2; jj++) {
#pragma unroll
                for (int r = 0; r < 4; r++) {
                    float v = acc[i][jj][r];
                    float e = __expf((gate == 2) ? -2.0f * v : -v);
                    float s = 1.0f / (1.0f + e);
                    acc[i][jj][r] = (gate == 2) ? 2.0f * s - 1.0f : s;
                }
#pragma unroll
                for (int r = 0; r < 4; r++) {
                    float nv = acc[i][jj][r];          // i-gate on writer lanes
                    float f1 = __shfl_xor(nv, 1);      // f
                    float f2 = __shfl_xor(nv, 2);      // c~ (tanh'd)
                    float f3 = __shfl_xor(nv, 3);      // o
                    if (gate == 0) {
                        float cn = f1 * c_reg[i][jj][r] + nv * f2;
                        c_reg[i][jj][r] = cn;
                        float hv = f3 * tanhf_(cn);
                        int lrow = wm + i * 16 + lq * 4 + r;          // 0..63
                        int lu = (wn + jj * 16 + lr) >> 2;            // 0..15
                        hstage[lrow * 16 + lu] = __float2bfloat16(hv);
                    }
                }
            }

        __syncthreads();   // hstage complete (also guards hL reuse)

        // ---- coalesced h store: 128 threads x 16B consecutive, sc1 ----
        if (tid < 128) {
            int lrow = tid >> 1, half = tid & 1;
            union { short8 s; ull u[2]; } X;
            X.s = *(const short8*)(hstage + lrow * 16 + half * 8);
            ull* dst = (ull*)(hs + ((size_t)t * B_ + m0 + lrow) * U_ + j * 16 + half * 8);
            __hip_atomic_store(dst,     X.u[0], __ATOMIC_RELAXED, __HIP_MEMORY_SCOPE_AGENT);
            __hip_atomic_store(dst + 1, X.u[1], __ATOMIC_RELAXED, __HIP_MEMORY_SCOPE_AGENT);
        }

        // ---- signal: syncthreads drains vmcnt (stores acked), then flag ----
        if (t < T_ - 1) {
            __syncthreads();
            if (tid == 0)
                __hip_atomic_store(myflag, (unsigned)(t + 1), __ATOMIC_RELAXED, __HIP_MEMORY_SCOPE_AGENT);
        }
    }
}

// ---------------------------------------------------------------------------
// dense: out[M,N] = A[M,K](bf16,[T][B] rows) @ WT[N,K](bf16) + bias ;
// fp32 out written in harness [B][T] row order.
// ---------------------------------------------------------------------------
__global__ __launch_bounds__(256) void gemm_bias(
    const __hip_bfloat16* __restrict__ A, const __hip_bfloat16* __restrict__ WT,
    const float* __restrict__ bias, float* __restrict__ out, int K, int N) {
    const int m0 = blockIdx.x * 128, n0 = blockIdx.y * 64;
    const int tid = threadIdx.x, w = tid >> 6, l = tid & 63, lr = l & 15, lq = l >> 4;
    const int wm = w * 32;

    f32x4 acc[2][4];
#pragma unroll
    for (int jj = 0; jj < 4; jj++) {
        float bv = bias[n0 + jj * 16 + lr];
#pragma unroll
        for (int i = 0; i < 2; i++)
#pragma unroll
            for (int r = 0; r < 4; r++) acc[i][jj][r] = bv;
    }
    for (int k0 = 0; k0 < K; k0 += 32) {
        short8 a[2], b[4];
#pragma unroll
        for (int i = 0; i < 2; i++)
            a[i] = *(const short8*)(A + (size_t)(m0 + wm + i * 16 + lr) * K + k0 + lq * 8);
#pragma unroll
        for (int jj = 0; jj < 4; jj++)
            b[jj] = *(const short8*)(WT + (size_t)(n0 + jj * 16 + lr) * K + k0 + lq * 8);
#pragma unroll
        for (int i = 0; i < 2; i++)
#pragma unroll
            for (int jj = 0; jj < 4; jj++)
                acc[i][jj] = __builtin_amdgcn_mfma_f32_16x16x32_bf16(a[i], b[jj], acc[i][jj], 0, 0, 0);
    }
#pragma unroll
    for (int i = 0; i < 2; i++)
#pragma unroll
        for (int jj = 0; jj < 4; jj++)
#pragma unroll
            for (int r = 0; r < 4; r++) {
                int ra = m0 + wm + i * 16 + lq * 4 + r;     // = t*512 + b
                int rh = (ra & 511) * T_ + (ra >> 9);       // = b*T + t
                out[(size_t)rh * N + n0 + jj * 16 + lr] = acc[i][jj][r];
            }
}

// ---------------------------------------------------------------------------
// reparameterize: z = zm + exp(0.5*zlv)*eps (harness [B][T][Z] order);
// also emits exp(zlv) and bf16 z in [T][B][Z] layout for the decoder.
// ---------------------------------------------------------------------------
__global__ void reparam(const float* __restrict__ zm, const float* __restrict__ zlv,
                        const float* __restrict__ eps, float* __restrict__ z,
                        float* __restrict__ ezlv, __hip_bfloat16* __restrict__ zb, int n) {
    int i = blockIdx.x * 256 + threadIdx.x;
    if (i >= n) return;
    float m = zm[i], lv = zlv[i];
    float zi = m + expf(0.5f * lv) * eps[i];
    z[i] = zi;
    ezlv[i] = expf(lv);
    int b = i >> 13;                       // /(T*Z)=8192
    int rem = i & 8191;
    int t = rem >> 6, zc = rem & 63;       // Z=64
    zb[(((size_t)t << 9) + b) * Z_ + zc] = __float2bfloat16(zi);
}

// ---------------------------------------------------------------------------

extern "C" void kernel_launch(void* const* d_in, const int* in_sizes, int n_in,
                              void* d_out, int out_size, void* d_ws, size_t ws_size,
                              hipStream_t stream) {
    const float* x    = (const float*)d_in[0];
    const float* eps  = (const float*)d_in[1];
    const float* e0Wx = (const float*)d_in[2];
    const float* e0Wh = (const float*)d_in[3];
    const float* e0b  = (const float*)d_in[4];
    const float* e1Wx = (const float*)d_in[5];
    const float* e1Wh = (const float*)d_in[6];
    const float* e1b  = (const float*)d_in[7];
    const float* d0Wx = (const float*)d_in[8];
    const float* d0Wh = (const float*)d_in[9];
    const float* d0b  = (const float*)d_in[10];
    const float* d1Wx = (const float*)d_in[11];
    const float* d1Wh = (const float*)d_in[12];
    const float* d1b  = (const float*)d_in[13];
    const float* Wm   = (const float*)d_in[14];
    const float* bm   = (const float*)d_in[15];
    const float* Wv   = (const float*)d_in[16];
    const float* bv   = (const float*)d_in[17];
    const float* Wo   = (const float*)d_in[18];
    const float* bo   = (const float*)d_in[19];
    float* out = (float*)d_out;

    char* ws = (char*)d_ws;
    size_t off = 0;
    auto alloc = [&](size_t bytes) -> char* {
        off = (off + 255) & ~(size_t)255;
        char* p = ws + off;
        off += bytes;
        return p;
    };
    __hip_bfloat16* hsA  = (__hip_bfloat16*)alloc((size_t)B_ * T_ * U_ * 2); // 64MB, [T][B][U]
    __hip_bfloat16* hsB  = (__hip_bfloat16*)alloc((size_t)B_ * T_ * U_ * 2); // 64MB, [T][B][U]
    __hip_bfloat16* xb   = (__hip_bfloat16*)alloc((size_t)B_ * T_ * D_ * 2); // 16MB, [T][B][D]
    __hip_bfloat16* zb   = (__hip_bfloat16*)alloc((size_t)B_ * T_ * Z_ * 2); //  8MB, [T][B][Z]
    __hip_bfloat16* WTe0 = (__hip_bfloat16*)alloc((size_t)G4_ * (U_ + D_) * 2);
    __hip_bfloat16* WTe1 = (__hip_bfloat16*)alloc((size_t)G4_ * (U_ + U_) * 2);
    __hip_bfloat16* WTd0 = (__hip_bfloat16*)alloc((size_t)G4_ * (U_ + Z_) * 2);
    __hip_bfloat16* WTd1 = (__hip_bfloat16*)alloc((size_t)G4_ * (U_ + U_) * 2);
    __hip_bfloat16* WmT  = (__hip_bfloat16*)alloc((size_t)Z_ * U_ * 2);
    __hip_bfloat16* WvT  = (__hip_bfloat16*)alloc((size_t)Z_ * U_ * 2);
    __hip_bfloat16* WoT  = (__hip_bfloat16*)alloc((size_t)D_ * U_ * 2);
    float* be0 = (float*)alloc(G4_ * 4);
    float* be1 = (float*)alloc(G4_ * 4);
    float* bd0 = (float*)alloc(G4_ * 4);
    float* bd1 = (float*)alloc(G4_ * 4);
    unsigned* flags = (unsigned*)alloc(4 * 8 * 32 * 16 * sizeof(unsigned)); // 64KB, 64B-padded

    hipMemsetAsync(flags, 0, 4 * 8 * 32 * 16 * sizeof(unsigned), stream);

    // ---- prep: bf16 conversions + weight transpose/permutes ----
    convert_transpose<<<(B_ * T_ * D_ + 255) / 256, 256, 0, stream>>>(x, xb);

    auto cw = [&](const float* src, __hip_bfloat16* dst, int K, int Nrows, int Nsrc, int ldd, int koff, int perm) {
        conv_weight<<<(K * Nrows + 255) / 256, 256, 0, stream>>>(src, dst, K, Nrows, Nsrc, ldd, koff, perm);
    };
    cw(e0Wh, WTe0, U_, G4_, G4_, U_ + D_, 0, 1);
    cw(e0Wx, WTe0, D_, G4_, G4_, U_ + D_, U_, 1);
    cw(e1Wh, WTe1, U_, G4_, G4_, U_ + U_, 0, 1);
    cw(e1Wx, WTe1, U_, G4_, G4_, U_ + U_, U_, 1);
    cw(d0Wh, WTd0, U_, G4_, G4_, U_ + Z_, 0, 1);
    cw(d0Wx, WTd0, Z_, G4_, G4_, U_ + Z_, U_, 1);
    cw(d1Wh, WTd1, U_, G4_, G4_, U_ + U_, 0, 1);
    cw(d1Wx, WTd1, U_, G4_, G4_, U_ + U_, U_, 1);
    cw(Wm, WmT, U_, Z_, Z_, U_, 0, 0);
    cw(Wv, WvT, U_, Z_, Z_, U_, 0, 0);
    cw(Wo, WoT, U_, D_, D_, U_, 0, 0);
    conv_bias<<<G4_ / 256, 256, 0, stream>>>(e0b, be0);
    conv_bias<<<G4_ / 256, 256, 0, stream>>>(e1b, be1);
    conv_bias<<<G4_ / 256, 256, 0, stream>>>(d0b, bd0);
    conv_bias<<<G4_ / 256, 256, 0, stream>>>(d1b, bd1);

    // ---- encoder (persistent layers) ----
    lstm_layer_persist<D_><<<256, 256, 0, stream>>>(hsA, xb, WTe0, be0, flags + 0 * 4096);
    lstm_layer_persist<U_><<<256, 256, 0, stream>>>(hsB, hsA, WTe1, be1, flags + 1 * 4096);

    // ---- latent heads + reparameterize ----
    const size_t oRecon = 0;
    const size_t oE   = (size_t)B_ * T_ * D_;
    const size_t oZm  = oE + (size_t)B_ * T_ * Z_;
    const size_t oZlv = oZm + (size_t)B_ * T_ * Z_;
    const size_t oZ   = oZlv + (size_t)B_ * T_ * Z_;

    gemm_bias<<<dim3(B_ * T_ / 128, Z_ / 64), 256, 0, stream>>>(hsB, WmT, bm, out + oZm, U_, Z_);
    gemm_bias<<<dim3(B_ * T_ / 128, Z_ / 64), 256, 0, stream>>>(hsB, WvT, bv, out + oZlv, U_, Z_);
    reparam<<<(B_ * T_ * Z_ + 255) / 256, 256, 0, stream>>>(out + oZm, out + oZlv, eps,
                                                            out + oZ, out + oE, zb, B_ * T_ * Z_);

    // ---- decoder (persistent layers) ----
    lstm_layer_persist<Z_><<<256, 256, 0, stream>>>(hsA, zb, WTd0, bd0, flags + 2 * 4096);
    lstm_layer_persist<U_><<<256, 256, 0, stream>>>(hsB, hsA, WTd1, bd1, flags + 3 * 4096);

    // ---- output dense ----
    gemm_bias<<<dim3(B_ * T_ / 128, D_ / 64), 256, 0, stream>>>(hsB, WoT, bo, out + oRecon, U_, D_);
}